// Round 1
// baseline (1474.374 us; speedup 1.0000x reference)
//
#include <hip/hip_runtime.h>
#include <stdint.h>

// HamiltonianFlow: x [256, 8, 32, 2] (q,p), H = 0.5*sum(p^2) + MLP(q).
// dq/dt = p, dp/dt = -W1 @ [(1-tanh(z)^2) * W2], z = q^T W1 + b1.
// 100 RK4 steps, dt=0.01. One persistent block per batch element (256 blocks,
// 1 per CU); W1 held in LDS as bf16 (RNE), state in registers, fp32 compute.

#define FEATN 256
#define HIDN  256
#define WSTRIDE 264   // bf16 elems/row: 528 B = 132 dwords (bank shift 4, 16B aligned)
#define NSTEPS 100

__device__ __forceinline__ float bflo(uint32_t w) {
    return __uint_as_float(w << 16);
}
__device__ __forceinline__ float bfhi(uint32_t w) {
    return __uint_as_float(w & 0xffff0000u);
}
__device__ __forceinline__ uint32_t f2bf_rne(float v) {
    uint32_t u = __float_as_uint(v);
    uint32_t r = u + 0x7fffu + ((u >> 16) & 1u);
    return r >> 16;
}

__global__ __launch_bounds__(256, 1)
void ham_kernel(const float* __restrict__ x0, const float* __restrict__ W1,
                const float* __restrict__ b1, const float* __restrict__ W2,
                float* __restrict__ out)
{
    __shared__ uint16_t Wl[FEATN * WSTRIDE];  // 135168 B
    __shared__ float zp[4][HIDN];             // forward partials per wave
    __shared__ float ush[HIDN];               // u_j = (1-h^2)*W2_j

    const int t = threadIdx.x;
    const int blk = blockIdx.x;

    // ---- stage W1 -> LDS as bf16 (round-to-nearest-even), coalesced float4 ----
    for (int k = t; k < (FEATN * HIDN / 4); k += 256) {
        const int row = k >> 6;
        const int c4 = (k & 63) * 4;
        const float4 v = *(const float4*)(W1 + row * HIDN + c4);
        uint32_t lo = f2bf_rne(v.x) | (f2bf_rne(v.y) << 16);
        uint32_t hi = f2bf_rne(v.z) | (f2bf_rne(v.w) << 16);
        *(uint2*)(&Wl[row * WSTRIDE + c4]) = make_uint2(lo, hi);
    }

    const float b1r = b1[t];
    const float w2r = W2[t];

    // state component t = d*32+nn; x layout: [...,(q,p)] interleaved
    float2 qp = ((const float2*)(x0 + (size_t)blk * 512))[t];
    float q0 = qp.x, p0 = qp.y;

    __syncthreads();

    const int wv = t >> 6;   // wave id = i-chunk of the forward reduction
    const int ln = t & 63;
    const float dt = 0.01f;

    for (int step = 0; step < NSTEPS; ++step) {
        float accq = 0.f, accp = 0.f;
        float qs = q0, ps = p0;
        #pragma unroll
        for (int s = 0; s < 4; ++s) {
            // ---- forward partial: zp[wv][j] = sum_{i in wave's 64 rows} q_i W[i][j]
            // wave wv's lanes own exactly q components [wv*64, wv*64+64): readlane.
            float a0 = 0.f, a1 = 0.f, a2 = 0.f, a3 = 0.f;
            const uint16_t* wb = &Wl[(wv * 64) * WSTRIDE + ln * 4];
            #pragma unroll 8
            for (int ii = 0; ii < 64; ++ii) {
                uint2 w = *(const uint2*)(wb + ii * WSTRIDE);  // W[i][4ln..4ln+3]
                float qi = __uint_as_float(
                    __builtin_amdgcn_readlane(__float_as_uint(qs), ii));
                a0 += bflo(w.x) * qi;
                a1 += bfhi(w.x) * qi;
                a2 += bflo(w.y) * qi;
                a3 += bfhi(w.y) * qi;
            }
            *(float4*)(&zp[wv][ln * 4]) = make_float4(a0, a1, a2, a3);
            __syncthreads();

            // ---- nonlinearity: z_t -> u_t (thread t owns hidden unit t)
            float z = b1r + ((zp[0][t] + zp[1][t]) + (zp[2][t] + zp[3][t]));
            float h = tanhf(z);
            ush[t] = (1.f - h * h) * w2r;
            __syncthreads();

            // ---- backward: g_t = sum_j W[t][j] u_j (thread t owns row t)
            const uint4* wrow = (const uint4*)(&Wl[t * WSTRIDE]);  // 528t: 16B aligned
            float g0 = 0.f, g1 = 0.f, g2 = 0.f, g3 = 0.f;
            #pragma unroll 4
            for (int jc = 0; jc < 32; ++jc) {
                uint4 w = wrow[jc];
                float4 ua = *(const float4*)(&ush[jc * 8]);
                float4 ub = *(const float4*)(&ush[jc * 8 + 4]);
                g0 += bflo(w.x) * ua.x + bfhi(w.x) * ua.y;
                g1 += bflo(w.y) * ua.z + bfhi(w.y) * ua.w;
                g2 += bflo(w.z) * ub.x + bfhi(w.z) * ub.y;
                g3 += bflo(w.w) * ub.z + bfhi(w.w) * ub.w;
            }
            float g = (g0 + g1) + (g2 + g3);

            // ---- RK4 bookkeeping (k = (ps, -g))
            float kq = ps, kp = -g;
            float wgt = (s == 0 || s == 3) ? 1.f : 2.f;
            accq += wgt * kq;
            accp += wgt * kp;
            if (s < 3) {
                float a = (s == 2) ? dt : 0.5f * dt;
                qs = q0 + a * kq;
                ps = p0 + a * kp;
            }
        }
        q0 += (dt / 6.f) * accq;
        p0 += (dt / 6.f) * accp;
    }

    ((float2*)(out + (size_t)blk * 512))[t] = make_float2(q0, p0);
}

extern "C" void kernel_launch(void* const* d_in, const int* in_sizes, int n_in,
                              void* d_out, int out_size, void* d_ws, size_t ws_size,
                              hipStream_t stream) {
    const float* x0 = (const float*)d_in[0];
    const float* W1 = (const float*)d_in[1];
    const float* b1 = (const float*)d_in[2];
    const float* W2 = (const float*)d_in[3];
    // d_in[4] = b2: constant offset, no effect on the gradient/dynamics.
    float* out = (float*)d_out;
    hipLaunchKernelGGL(ham_kernel, dim3(256), dim3(256), 0, stream,
                       x0, W1, b1, W2, out);
}

// Round 3
// 674.223 us; speedup vs baseline: 2.1868x; 2.1868x over previous
//
#include <hip/hip_runtime.h>
#include <hip/hip_fp16.h>
#include <stdint.h>

// HamiltonianFlow: x [256, 8, 32, 2] (q,p); H = 0.5*sum(p^2) + MLP(q).
// dq/dt = p, dp/dt = -W1 @ [(1-tanh(z)^2) * W2], z = q^T W1 + b1.
// 100 RK4 steps (400 sequential MLP fwd+bwd evals).
//
// R3: one block / batch element (256 blocks, 1/CU), 1024 threads (16 waves,
// 4/SIMD). W1 in REGISTERS, packed f16, both orientations (64 VGPRs/thread).
// All matvec FMAs via v_fma_mix_f32: f16 operands converted EXACTLY to f32,
// true fp32 FMA (R2's v_dot2_f32_bf16 showed ~2e-3 relative product-rounding
// error that amplified 28x over the trajectory; fma_mix has none).
// f16 storage (10-bit mantissa) beats R1's bf16 (7-bit) 4x on weight error.
// Only d==0 waves (one per SIMD) hold state / do nonlinearity+RK4 bookkeeping;
// q and u broadcast via tiny packed-f16 LDS arrays, wave-uniform b128 reads.

#define NSTEPS 100

__device__ __forceinline__ uint16_t h16(float x) {
    return __half_as_ushort(__float2half_rn(x));
}
__device__ __forceinline__ uint32_t packh2(float a, float b) {
    return (uint32_t)h16(a) | ((uint32_t)h16(b) << 16);
}

// acc += f32(f16 half of w) * f32(f16 half of x)  -- exact fp32 fma
#define FMAMIX_LL(acc, w, x) \
    asm("v_fma_mix_f32 %0, %1, %2, %0 op_sel:[0,0,0] op_sel_hi:[1,1,0]" \
        : "+v"(acc) : "v"(w), "v"(x))
#define FMAMIX_HH(acc, w, x) \
    asm("v_fma_mix_f32 %0, %1, %2, %0 op_sel:[1,1,0] op_sel_hi:[1,1,0]" \
        : "+v"(acc) : "v"(w), "v"(x))

__global__ __launch_bounds__(1024, 1)
void ham_kernel(const float* __restrict__ x0, const float* __restrict__ W1,
                const float* __restrict__ b1, const float* __restrict__ W2,
                float* __restrict__ out)
{
    __shared__ __align__(16) uint16_t qsh[256];  // q broadcast, packed f16
    __shared__ __align__(16) uint16_t ush[256];  // u broadcast, packed f16
    __shared__ float zp[4][256];                 // forward quarter partials
    __shared__ float gp[4][256];                 // backward quarter partials

    const int t = threadIdx.x;
    const int d = t >> 8;    // quarter (wave-uniform: waves 4d..4d+3)
    const int r = t & 255;
    const int blk = blockIdx.x;

    // ---- W1 -> registers, packed f16, both orientations ----
    // wrow[m]: (W[r][64d+2m], W[r][64d+2m+1])   (backward, row r)
    // wcol[m]: (W[64d+2m][r], W[64d+2m+1][r])   (forward, column r)
    uint32_t wrow[32], wcol[32];
    {
        const float* Wr = W1 + r * 256 + d * 64;
        #pragma unroll 4
        for (int k = 0; k < 16; ++k) {
            float4 v = *(const float4*)(Wr + 4 * k);
            wrow[2 * k]     = packh2(v.x, v.y);
            wrow[2 * k + 1] = packh2(v.z, v.w);
        }
        const float* Wc = W1 + (d * 64) * 256 + r;  // lanes coalesced over r
        #pragma unroll 8
        for (int k = 0; k < 32; ++k)
            wcol[k] = packh2(Wc[(2 * k) * 256], Wc[(2 * k + 1) * 256]);
    }
    const float b1r = b1[r];
    const float w2r = W2[r];

    // state lives only in d==0 threads (waves 0..3, one per SIMD)
    float q0 = 0.f, p0 = 0.f;
    if (d == 0) {
        float2 qp = ((const float2*)(x0 + (size_t)blk * 512))[r];
        q0 = qp.x; p0 = qp.y;
        qsh[r] = h16(q0);
    }
    __syncthreads();

    const float dt = 0.01f;
    float accq = 0.f, accp = 0.f, qs = q0, ps = p0;

    #pragma unroll 1
    for (int it = 0; it < NSTEPS * 4; ++it) {
        const int s = it & 3;

        // ---- forward quarter: zp[d][r] = sum_{i in [64d,64d+64)} q_i W[i][r]
        {
            float a0 = 0.f, a1 = 0.f, a2 = 0.f, a3 = 0.f;
            const uint4* qv4 = (const uint4*)(qsh + 64 * d);  // uniform addr
            #pragma unroll
            for (int kk = 0; kk < 8; ++kk) {
                uint4 qv = qv4[kk];
                FMAMIX_LL(a0, wcol[4 * kk + 0], qv.x);
                FMAMIX_HH(a1, wcol[4 * kk + 0], qv.x);
                FMAMIX_LL(a2, wcol[4 * kk + 1], qv.y);
                FMAMIX_HH(a3, wcol[4 * kk + 1], qv.y);
                FMAMIX_LL(a0, wcol[4 * kk + 2], qv.z);
                FMAMIX_HH(a1, wcol[4 * kk + 2], qv.z);
                FMAMIX_LL(a2, wcol[4 * kk + 3], qv.w);
                FMAMIX_HH(a3, wcol[4 * kk + 3], qv.w);
            }
            zp[d][r] = (a0 + a1) + (a2 + a3);
        }
        __syncthreads();

        // ---- nonlinearity: d==0 waves only
        if (d == 0) {
            float z = ((zp[0][r] + zp[1][r]) + (zp[2][r] + zp[3][r])) + b1r;
            float e = __expf(2.f * z);          // tanh via exp; saturates ok
            float h = 1.f - 2.f / (e + 1.f);
            float u = (1.f - h * h) * w2r;
            ush[r] = h16(u);
        }
        __syncthreads();

        // ---- backward quarter: gp[d][r] = sum_{j in [64d,64d+64)} W[r][j] u_j
        {
            float g0 = 0.f, g1 = 0.f, g2 = 0.f, g3 = 0.f;
            const uint4* uv4 = (const uint4*)(ush + 64 * d);  // uniform addr
            #pragma unroll
            for (int kk = 0; kk < 8; ++kk) {
                uint4 uv = uv4[kk];
                FMAMIX_LL(g0, wrow[4 * kk + 0], uv.x);
                FMAMIX_HH(g1, wrow[4 * kk + 0], uv.x);
                FMAMIX_LL(g2, wrow[4 * kk + 1], uv.y);
                FMAMIX_HH(g3, wrow[4 * kk + 1], uv.y);
                FMAMIX_LL(g0, wrow[4 * kk + 2], uv.z);
                FMAMIX_HH(g1, wrow[4 * kk + 2], uv.z);
                FMAMIX_LL(g2, wrow[4 * kk + 3], uv.w);
                FMAMIX_HH(g3, wrow[4 * kk + 3], uv.w);
            }
            gp[d][r] = (g0 + g1) + (g2 + g3);
        }
        __syncthreads();

        // ---- RK4 bookkeeping: d==0 waves only
        if (d == 0) {
            float g = (gp[0][r] + gp[1][r]) + (gp[2][r] + gp[3][r]);
            float kq = ps, kp = -g;
            float wgt = (s == 0 || s == 3) ? 1.f : 2.f;
            accq += wgt * kq;
            accp += wgt * kp;
            float qn;
            if (s < 3) {
                float a = (s == 2) ? dt : 0.5f * dt;
                qs = q0 + a * kq;
                ps = p0 + a * kp;
                qn = qs;
            } else {
                q0 += (dt / 6.f) * accq;
                p0 += (dt / 6.f) * accp;
                accq = 0.f; accp = 0.f;
                qs = q0; ps = p0;
                qn = q0;
            }
            qsh[r] = h16(qn);
        }
        __syncthreads();
    }

    if (d == 0)
        ((float2*)(out + (size_t)blk * 512))[r] = make_float2(q0, p0);
}

extern "C" void kernel_launch(void* const* d_in, const int* in_sizes, int n_in,
                              void* d_out, int out_size, void* d_ws, size_t ws_size,
                              hipStream_t stream) {
    const float* x0 = (const float*)d_in[0];
    const float* W1 = (const float*)d_in[1];
    const float* b1 = (const float*)d_in[2];
    const float* W2 = (const float*)d_in[3];
    // d_in[4] = b2: constant offset, no effect on the gradient/dynamics.
    float* out = (float*)d_out;
    hipLaunchKernelGGL(ham_kernel, dim3(256), dim3(1024), 0, stream,
                       x0, W1, b1, W2, out);
}